// Round 1
// baseline (529.325 us; speedup 1.0000x reference)
//
#include <hip/hip_runtime.h>

constexpr int   FEAT   = 128;
constexpr int   BATCH  = 512;
constexpr int   NNEG   = 4096;
constexpr long  NDATA  = 1200000;
constexpr int   CHUNKS = 8;                       // k-chunks per row in negsim
constexpr float INV_TEMP = 14.285714285714286f;   // 1/0.07 (max possible logit)
constexpr float LOG2E    = 1.4426950408889634f;
constexpr float LN2      = 0.6931471805599453f;
constexpr float K1       = INV_TEMP * LOG2E;      // logit->exp2 scale

// ---------------- prep: normalize s,t and compute pos logit ----------------
__global__ __launch_bounds__(128) void prep_kernel(
    const float* __restrict__ sf, const float* __restrict__ tf,
    float* __restrict__ s_n, float* __restrict__ t_n, float* __restrict__ pos) {
  const int b = blockIdx.x, t = threadIdx.x;
  const float sv = sf[b * FEAT + t];
  const float tv = tf[b * FEAT + t];
  float ss = sv * sv, tt = tv * tv, st = sv * tv;
#pragma unroll
  for (int m = 1; m < 64; m <<= 1) {
    ss += __shfl_xor(ss, m);
    tt += __shfl_xor(tt, m);
    st += __shfl_xor(st, m);
  }
  __shared__ float sh[6];
  if ((t & 63) == 0) {
    const int w = t >> 6;
    sh[w * 3 + 0] = ss; sh[w * 3 + 1] = tt; sh[w * 3 + 2] = st;
  }
  __syncthreads();
  ss = sh[0] + sh[3]; tt = sh[1] + sh[4]; st = sh[2] + sh[5];
  const float snorm = fmaxf(sqrtf(ss), 1e-12f);
  const float tnorm = fmaxf(sqrtf(tt), 1e-12f);
  s_n[b * FEAT + t] = sv / snorm;
  t_n[b * FEAT + t] = tv / tnorm;
  if (t == 0) pos[b] = st / (snorm * tnorm) * INV_TEMP;
}

// ------------- negsim: gathered dots + partial sum of exp(logit-C) ---------
__global__ __launch_bounds__(256) void negsim_kernel(
    const float* __restrict__ neg, const int* __restrict__ nidx,
    const float* __restrict__ s_n, float* __restrict__ sumexp) {
  const int blk   = blockIdx.x;
  const int b     = blk >> 3;          // row
  const int chunk = blk & (CHUNKS - 1);
  const int lane  = threadIdx.x & 63;
  const int w     = threadIdx.x >> 6;  // wave id (0..3)
  const float2 s2 = *(const float2*)(s_n + b * FEAT + 2 * lane);
  constexpr int KPC = NNEG / CHUNKS;   // 512 k per chunk
  constexpr int KPW = KPC / 4;         // 128 k per wave
  const int* row_idx = nidx + b * NNEG + chunk * KPC + w * KPW;
  float acc = 0.f;
  for (int k = 0; k < KPW; k += 4) {
    const int i0 = row_idx[k + 0];
    const int i1 = row_idx[k + 1];
    const int i2 = row_idx[k + 2];
    const int i3 = row_idx[k + 3];
    const float2 n0 = *(const float2*)(neg + i0 * FEAT + 2 * lane);
    const float2 n1 = *(const float2*)(neg + i1 * FEAT + 2 * lane);
    const float2 n2 = *(const float2*)(neg + i2 * FEAT + 2 * lane);
    const float2 n3 = *(const float2*)(neg + i3 * FEAT + 2 * lane);
    float p0 = fmaf(s2.x, n0.x, s2.y * n0.y);
    float p1 = fmaf(s2.x, n1.x, s2.y * n1.y);
    float p2 = fmaf(s2.x, n2.x, s2.y * n2.y);
    float p3 = fmaf(s2.x, n3.x, s2.y * n3.y);
#pragma unroll
    for (int m = 1; m < 64; m <<= 1) {
      p0 += __shfl_xor(p0, m);
      p1 += __shfl_xor(p1, m);
      p2 += __shfl_xor(p2, m);
      p3 += __shfl_xor(p3, m);
    }
    // exp(logit - C) = exp2(cos*K1 - K1), cos <= 1 so arg <= 0 (no overflow)
    acc += exp2f(fmaf(p0, K1, -K1));
    acc += exp2f(fmaf(p1, K1, -K1));
    acc += exp2f(fmaf(p2, K1, -K1));
    acc += exp2f(fmaf(p3, K1, -K1));
  }
  __shared__ float part[4];
  if (lane == 0) part[w] = acc;
  __syncthreads();
  if (threadIdx.x == 0)
    sumexp[b * CHUNKS + chunk] = part[0] + part[1] + part[2] + part[3];
}

// --------------- loss: logsumexp per row, mean over rows -------------------
__global__ __launch_bounds__(512) void loss_kernel(
    const float* __restrict__ pos, const float* __restrict__ sumexp,
    float* __restrict__ out) {
  const int t = threadIdx.x;
  const float p = pos[t];
  float tot = exp2f(fmaf(p, LOG2E, -K1));  // exp(p - C)
#pragma unroll
  for (int c = 0; c < CHUNKS; ++c) tot += sumexp[t * CHUNKS + c];
  float l = INV_TEMP + log2f(tot) * LN2 - p;  // C + ln(tot) - p
#pragma unroll
  for (int m = 1; m < 64; m <<= 1) l += __shfl_xor(l, m);
  __shared__ float sh[8];
  if ((t & 63) == 0) sh[t >> 6] = l;
  __syncthreads();
  if (t == 0) {
    float s = 0.f;
#pragma unroll
    for (int i = 0; i < 8; ++i) s += sh[i];
    out[0] = s / (float)BATCH;
  }
}

// --------------------- copy bank -> output ---------------------------------
__global__ __launch_bounds__(256) void copy_kernel(
    const float* __restrict__ src, float* __restrict__ dst, long n) {
  long i = (long)blockIdx.x * blockDim.x + threadIdx.x;
  const long stride = (long)gridDim.x * blockDim.x;
  for (; i + 3 * stride < n; i += 4 * stride) {
    const float a = src[i];
    const float b = src[i + stride];
    const float c = src[i + 2 * stride];
    const float d = src[i + 3 * stride];
    dst[i] = a;
    dst[i + stride] = b;
    dst[i + 2 * stride] = c;
    dst[i + 3 * stride] = d;
  }
  for (; i < n; i += stride) dst[i] = src[i];
}

// ------------- EMA scatter update with last-writer-wins --------------------
__global__ __launch_bounds__(128) void update_kernel(
    const float* __restrict__ neg, const float* __restrict__ t_n,
    const int* __restrict__ indices, float* __restrict__ dst) {
  const int b = blockIdx.x, t = threadIdx.x;
  const int idx = indices[b];
  __shared__ int skip;
  if (t == 0) {
    int s = 0;
    for (int b2 = b + 1; b2 < BATCH; ++b2)
      if (indices[b2] == idx) { s = 1; break; }
    skip = s;
  }
  __syncthreads();
  if (skip) return;  // a later batch element writes this row (last wins)
  const float u = 0.5f * neg[(long)idx * FEAT + t] + 0.5f * t_n[b * FEAT + t];
  float uu = u * u;
#pragma unroll
  for (int m = 1; m < 64; m <<= 1) uu += __shfl_xor(uu, m);
  __shared__ float sh2[2];
  if ((t & 63) == 0) sh2[t >> 6] = uu;
  __syncthreads();
  const float nrm = fmaxf(sqrtf(sh2[0] + sh2[1]), 1e-12f);
  dst[(long)idx * FEAT + t] = u / nrm;
}

extern "C" void kernel_launch(void* const* d_in, const int* in_sizes, int n_in,
                              void* d_out, int out_size, void* d_ws, size_t ws_size,
                              hipStream_t stream) {
  const float* student   = (const float*)d_in[0];
  const float* teacher   = (const float*)d_in[1];
  const float* negatives = (const float*)d_in[2];
  const int*   indices   = (const int*)d_in[3];
  const int*   neg_idx   = (const int*)d_in[4];
  float* out = (float*)d_out;

  float* ws     = (float*)d_ws;
  float* s_n    = ws;                        // [512*128]
  float* t_n    = s_n + BATCH * FEAT;        // [512*128]
  float* pos    = t_n + BATCH * FEAT;        // [512]
  float* sumexp = pos + BATCH;               // [512*CHUNKS]

  prep_kernel<<<BATCH, 128, 0, stream>>>(student, teacher, s_n, t_n, pos);
  negsim_kernel<<<BATCH * CHUNKS, 256, 0, stream>>>(negatives, neg_idx, s_n, sumexp);
  loss_kernel<<<1, 512, 0, stream>>>(pos, sumexp, out);
  copy_kernel<<<2048, 256, 0, stream>>>(negatives, out + 1, NDATA * (long)FEAT);
  update_kernel<<<BATCH, 128, 0, stream>>>(negatives, t_n, indices, out + 1);
}